// Round 3
// baseline (18.912 us; speedup 1.0000x reference)
//
#include <hip/hip_runtime.h>

// KANRNNEncoder: the T=1024 scan has dependency horizon 2 (only h[:, :24]
// feeds the recurrence, and those columns are pure functions of x at the
// previous step). Entire scan collapses to a closed form over x[:, T-2:T, :].
//
// R1: W_lat staged in LDS (coalesced), lane-rotated dot. 14.2 -> 10.4 us.
// R2: occupancy was 1 wave/SIMD (1024 waves total) -> all latency exposed.
//     Split K in half per wave: grid 512, block 256, 2 batch rows/block,
//     wave = (row, K-half). LDS ~66.5KB -> 2 blocks/CU = 2 waves/SIMD,
//     per-wave dot work halved. Partials combined through LDS.

constexpr int Bc = 1024, Tc = 1024, Fc = 8, Hc = 256, Kc = 8, Lc = 64;

__device__ __forceinline__ float sigm(float v) {
    return 1.0f / (1.0f + __expf(-v));
}

__global__ __launch_bounds__(256) void kan_rnn_collapsed(
    const float* __restrict__ x,     // (B,T,F)
    const float* __restrict__ a_in,  // (F,K) flat 64
    const float* __restrict__ b_in,  // (F,K)
    const float* __restrict__ a_h,   // (H,K) flat 2048
    const float* __restrict__ b_h,   // (H,K)
    const float* __restrict__ W,     // (L,H) 64x256
    const float* __restrict__ bl,    // (L,)
    float* __restrict__ out)         // (B,L)
{
    __shared__ float Ws[Lc * Hc];        // 64 KB
    __shared__ float hTs[2][Hc];         // one hT per batch row in block
    __shared__ float part[2][2][Lc];     // [row][khalf][lane]
    const int t   = threadIdx.x;
    const int w   = t >> 6;              // wave 0..3
    const int l   = t & 63;              // lane
    const int rib = w >> 1;              // row-in-block 0..1
    const int kh  = w & 1;               // K-half 0..1
    const int b   = blockIdx.x * 2 + rib;

    // ---- stage W into LDS, coalesced float4 (all 4 waves) ----
    {
        const float4* Wg = reinterpret_cast<const float4*>(W);
        float4* Wl = reinterpret_cast<float4*>(Ws);
        #pragma unroll
        for (int k = 0; k < (Lc * Hc / 4) / 256; ++k)   // 16 iters
            Wl[t + 256 * k] = Wg[t + 256 * k];
    }

    // ---- closed-form hT (only the kh==0 wave of each row; wave-uniform) ----
    if (kh == 0) {
        const float* xb = x + (size_t)b * Tc * Fc;
        const float x1  = xb[(Tc - 1) * Fc + (l >> 3)];  // x[b, T-1, l/8]
        const float x2v[3] = { xb[(Tc - 2) * Fc + 0],
                               xb[(Tc - 2) * Fc + 1],
                               xb[(Tc - 2) * Fc + 2] };

        hTs[rib][l] = sigm(2.0f * sigm(a_in[l] * (x1 - b_in[l])));

        const int hp0 = l >> 3;          // l/8 in 0..7
        #pragma unroll
        for (int m = 0; m < 3; ++m) {
            const int hp = hp0 + 8 * m;  // h' in 0..23
            const int j  = l + 64 * m;   // j  in 0..191
            const float s  = sigm(2.0f * sigm(a_in[hp] * (x2v[m] - b_in[hp])));
            hTs[rib][64 + j] = sigm(2.0f * sigm(a_h[j] * (s - b_h[j])));
        }
    }
    __syncthreads();

    // ---- half-dot: lane l accumulates W[l][K-half] . hT[row][K-half] ----
    // Chunk rotation by lane: lanes spread over all bank groups (<=2-way
    // aliasing = free); lanes l and l+32 share chunk index but read
    // different... same row l? no: lane owns W row l, rows 1KB apart are
    // bank-identical, rotation de-conflicts; (l, l+32) pairs are 2-way = free.
    const float4* Wrow = reinterpret_cast<const float4*>(Ws) + l * (Hc / 4);
    const float4* hrow = reinterpret_cast<const float4*>(hTs[rib]);
    const int qbase = 32 * kh;
    float a0 = 0.f, a1 = 0.f, a2 = 0.f, a3 = 0.f;
    #pragma unroll
    for (int i = 0; i < 32; i += 4) {
        const int q0 = qbase + ((i + 0 + l) & 31);
        const int q1 = qbase + ((i + 1 + l) & 31);
        const int q2 = qbase + ((i + 2 + l) & 31);
        const int q3 = qbase + ((i + 3 + l) & 31);
        float4 wv, hv;
        wv = Wrow[q0]; hv = hrow[q0];
        a0 += wv.x * hv.x + wv.y * hv.y + wv.z * hv.z + wv.w * hv.w;
        wv = Wrow[q1]; hv = hrow[q1];
        a1 += wv.x * hv.x + wv.y * hv.y + wv.z * hv.z + wv.w * hv.w;
        wv = Wrow[q2]; hv = hrow[q2];
        a2 += wv.x * hv.x + wv.y * hv.y + wv.z * hv.z + wv.w * hv.w;
        wv = Wrow[q3]; hv = hrow[q3];
        a3 += wv.x * hv.x + wv.y * hv.y + wv.z * hv.z + wv.w * hv.w;
    }
    part[rib][kh][l] = (a0 + a1) + (a2 + a3);
    __syncthreads();

    // ---- combine K-halves and store (kh==0 waves; wave-uniform branch) ----
    if (kh == 0) {
        out[(size_t)b * Lc + l] = bl[l] + part[rib][0][l] + part[rib][1][l];
    }
}

extern "C" void kernel_launch(void* const* d_in, const int* in_sizes, int n_in,
                              void* d_out, int out_size, void* d_ws, size_t ws_size,
                              hipStream_t stream) {
    const float* x    = (const float*)d_in[0];
    const float* a_in = (const float*)d_in[1];
    const float* b_in = (const float*)d_in[2];
    const float* a_h  = (const float*)d_in[3];
    const float* b_h  = (const float*)d_in[4];
    const float* W    = (const float*)d_in[5];
    const float* bl   = (const float*)d_in[6];
    float* out = (float*)d_out;

    dim3 grid(Bc / 2), block(256);
    kan_rnn_collapsed<<<grid, block, 0, stream>>>(x, a_in, b_in, a_h, b_h, W, bl, out);
}

// Round 4
// 9.642 us; speedup vs baseline: 1.9614x; 1.9614x over previous
//
#include <hip/hip_runtime.h>
#include <stdint.h>

// KANRNNEncoder: T=1024 scan has dependency horizon 2 (only h[:, :24] feeds
// the recurrence, and those columns are pure functions of x at the previous
// step). Entire scan collapses to a closed form over x[:, T-2:T, :].
//
// R1: W_lat staged in LDS (coalesced), lane-rotated dot.      14.2 -> 10.4 us
// R2: K-split via MORE BLOCKS (512 blocks x 2 rows): REGRESSED to 18.9 us —
//     per-block W staging is the dominant fixed cost; doubling blocks
//     doubled it. More waves must come from inside the block.
// R3: grid=256 (1 block/CU), 512 threads (8 waves = 2/SIMD), 4 rows/block,
//     wave pair per row splits the dot into K-halves; W staged via
//     global_load_lds width=16 (async, overlaps hT compute); hT compute
//     balanced across the wave pair.

constexpr int Bc = 1024, Tc = 1024, Fc = 8, Hc = 256, Kc = 8, Lc = 64;

__device__ __forceinline__ float sigm(float v) {
    return 1.0f / (1.0f + __expf(-v));
}

__global__ __launch_bounds__(512) void kan_rnn_collapsed(
    const float* __restrict__ x,     // (B,T,F)
    const float* __restrict__ a_in,  // (F,K) flat 64
    const float* __restrict__ b_in,  // (F,K)
    const float* __restrict__ a_h,   // (H,K) flat 2048
    const float* __restrict__ b_h,   // (H,K)
    const float* __restrict__ W,     // (L,H) 64x256
    const float* __restrict__ bl,    // (L,)
    float* __restrict__ out)         // (B,L)
{
    __shared__ float Ws[Lc * Hc];    // 64 KB
    __shared__ float hTs[4][Hc];     // 4 KB: one hT per row in block
    __shared__ float part[4][Lc];    // 1 KB: kh=1 partials
    const int t   = threadIdx.x;
    const int w   = t >> 6;          // wave 0..7
    const int l   = t & 63;          // lane
    const int rib = w >> 1;          // row-in-block 0..3
    const int kh  = w & 1;           // K-half 0..1
    const int b   = blockIdx.x * 4 + rib;

    // ---- async stage W -> LDS: 8 issues x 512 threads x 16B = 64 KB ----
    // Linear LDS layout matches the wave-uniform-base + lane*16 DMA pattern.
    {
        const char* gsrc = (const char*)W + t * 16;
        char*       ldst = (char*)&Ws[0] + t * 16;
        #pragma unroll
        for (int k = 0; k < 8; ++k) {
            __builtin_amdgcn_global_load_lds(
                (const __attribute__((address_space(1))) uint32_t*)(gsrc + k * 8192),
                (__attribute__((address_space(3))) uint32_t*)(ldst + k * 8192),
                16, 0, 0);
        }
    }

    // ---- closed-form hT, split across the row's wave pair ----
    // hT[c]: c= l (input basis @T-1);  c=64+j, j=l+64m, m=0,1,2 (hidden basis
    // of s_{h'}, h'=(l>>3)+8m, which is the input basis @T-2 feature m).
    const float* xb  = x + (size_t)b * Tc * Fc;
    const int    hp0 = l >> 3;
    if (kh == 0) {   // entries c = l and c = 64+l   (m=0)
        const float x1  = xb[(Tc - 1) * Fc + hp0];
        const float x20 = xb[(Tc - 2) * Fc + 0];
        hTs[rib][l]      = sigm(2.0f * sigm(a_in[l]   * (x1  - b_in[l])));
        const float s0   = sigm(2.0f * sigm(a_in[hp0] * (x20 - b_in[hp0])));
        hTs[rib][64 + l] = sigm(2.0f * sigm(a_h[l]    * (s0  - b_h[l])));
    } else {         // entries c = 128+l (m=1) and c = 192+l (m=2)
        const float x21 = xb[(Tc - 2) * Fc + 1];
        const float x22 = xb[(Tc - 2) * Fc + 2];
        const int hp1 = hp0 + 8,  hp2 = hp0 + 16;
        const int j1  = l + 64,   j2  = l + 128;
        const float s1 = sigm(2.0f * sigm(a_in[hp1] * (x21 - b_in[hp1])));
        hTs[rib][64 + j1] = sigm(2.0f * sigm(a_h[j1] * (s1 - b_h[j1])));
        const float s2 = sigm(2.0f * sigm(a_in[hp2] * (x22 - b_in[hp2])));
        hTs[rib][64 + j2] = sigm(2.0f * sigm(a_h[j2] * (s2 - b_h[j2])));
    }
    __syncthreads();   // drains gload_lds (vmcnt) + hT writes (lgkm)

    // ---- half-dot: lane l accumulates W[l][K-half] . hT[rib][K-half] ----
    // Rotation by lane: lanes 0-31 cover 32 consecutive 16B chunks; lanes
    // l and l+32 read the same chunk index (2-way, free).
    const float4* Wrow = reinterpret_cast<const float4*>(Ws) + l * (Hc / 4);
    const float4* hrow = reinterpret_cast<const float4*>(hTs[rib]);
    const int qb = 32 * kh;
    float a0 = 0.f, a1 = 0.f, a2 = 0.f, a3 = 0.f;
    #pragma unroll
    for (int i = 0; i < 32; i += 4) {
        const int q0 = qb + ((i + 0 + l) & 31);
        const int q1 = qb + ((i + 1 + l) & 31);
        const int q2 = qb + ((i + 2 + l) & 31);
        const int q3 = qb + ((i + 3 + l) & 31);
        float4 wv, hv;
        wv = Wrow[q0]; hv = hrow[q0];
        a0 += wv.x * hv.x + wv.y * hv.y + wv.z * hv.z + wv.w * hv.w;
        wv = Wrow[q1]; hv = hrow[q1];
        a1 += wv.x * hv.x + wv.y * hv.y + wv.z * hv.z + wv.w * hv.w;
        wv = Wrow[q2]; hv = hrow[q2];
        a2 += wv.x * hv.x + wv.y * hv.y + wv.z * hv.z + wv.w * hv.w;
        wv = Wrow[q3]; hv = hrow[q3];
        a3 += wv.x * hv.x + wv.y * hv.y + wv.z * hv.z + wv.w * hv.w;
    }
    const float p = (a0 + a1) + (a2 + a3);
    if (kh == 1) part[rib][l] = p;
    __syncthreads();

    if (kh == 0)
        out[(size_t)b * Lc + l] = bl[l] + p + part[rib][l];
}

extern "C" void kernel_launch(void* const* d_in, const int* in_sizes, int n_in,
                              void* d_out, int out_size, void* d_ws, size_t ws_size,
                              hipStream_t stream) {
    const float* x    = (const float*)d_in[0];
    const float* a_in = (const float*)d_in[1];
    const float* b_in = (const float*)d_in[2];
    const float* a_h  = (const float*)d_in[3];
    const float* b_h  = (const float*)d_in[4];
    const float* W    = (const float*)d_in[5];
    const float* bl   = (const float*)d_in[6];
    float* out = (float*)d_out;

    dim3 grid(Bc / 4), block(512);
    kan_rnn_collapsed<<<grid, block, 0, stream>>>(x, a_in, b_in, a_h, b_h, W, bl, out);
}